// Round 4
// baseline (2392.526 us; speedup 1.0000x reference)
//
#include <hip/hip_runtime.h>
#include <hip/hip_bf16.h>

// B=2, S=2048 -> M=4096 tokens, K=4096, NN=11008, groupsize=128.
static constexpr int M  = 4096;
static constexpr int K  = 4096;
static constexpr int NN = 11008;

typedef _Float16 f16;
typedef _Float16 f16x2 __attribute__((ext_vector_type(2)));
typedef _Float16 f16x8 __attribute__((ext_vector_type(8)));
typedef float    f32x4 __attribute__((ext_vector_type(4)));

// ---------------------------------------------------------------------------
// GPTQ nibble j of an int32 covers k = 8r+j. The magic unpack produces the
// interleaved order: position p holds actual k-offset (p>>1) + (p&1)*4.
// All fp16 tensors (xp, Wg', Wu', Wd', h) use this same within-8 permutation
// along the reduction dim, so dot products are consistent.
// Numerics: (1024+w) and (1025+z) are exact fp16 integers; their difference is
// exact; single rounding at the final mul by s (verified round 3, absmax 16).
// ---------------------------------------------------------------------------
union dq_u { f16x2 h[4]; f16x8 v; };

__device__ __forceinline__ f16x8 dq8(unsigned q, f16x2 s2, f16x2 zc2) {
    dq_u u;
    unsigned t0 = ( q         & 0x000F000Fu) | 0x64006400u;
    unsigned t1 = ((q >> 4)   & 0x000F000Fu) | 0x64006400u;
    unsigned t2 = ((q >> 8)   & 0x000F000Fu) | 0x64006400u;
    unsigned t3 = ((q >> 12)  & 0x000F000Fu) | 0x64006400u;
    u.h[0] = (__builtin_bit_cast(f16x2, t0) - zc2) * s2;
    u.h[1] = (__builtin_bit_cast(f16x2, t1) - zc2) * s2;
    u.h[2] = (__builtin_bit_cast(f16x2, t2) - zc2) * s2;
    u.h[3] = (__builtin_bit_cast(f16x2, t3) - zc2) * s2;
    return u.v;
}

// async global -> LDS, 16 B per lane. LDS dest = wave-uniform base + lane*16.
__device__ __forceinline__ void gll16(const f16* g, f16* l) {
    __builtin_amdgcn_global_load_lds(
        (const __attribute__((address_space(1))) unsigned int*)g,
        (__attribute__((address_space(3))) unsigned int*)l,
        16, 0, 0);
}

// Bank-swizzle: a 128(or 64)-row x 32-half tile is 4 chunks of 16B per row.
// Store global chunk c of row r at chunk slot (c + p(r)) & 3, p(r)=(r^(r>>2))&3.
// - Writes (global_load_lds): 4 consecutive lanes cover a permuted full 64B
//   row segment -> still coalesced.
// - Fragment reads (ds_read_b128, 16-lane phase = one quad, rows lr=0..15):
//   bank-quad = (4r + (q+p(r))&3) mod 8 hits each of 8 values exactly twice
//   -> 2 lanes/bank = free (m136).
__device__ __forceinline__ int swz_p(int r) { return (r ^ (r >> 2)) & 3; }

// decode staged slot s -> byte-less element offset r*ld + c*8 (halves)
__device__ __forceinline__ size_t swz_dec(int s, int ld) {
    int r  = s >> 2;
    int cp = s & 3;
    int c  = (cp - swz_p(r)) & 3;
    return (size_t)r * ld + c * 8;
}

// fragment-read LDS offset (halves) for row, wanted global chunk q
__device__ __forceinline__ int swz_read(int row, int q) {
    return (row * 4 + ((q + swz_p(row)) & 3)) * 8;
}

// ---------------------------------------------------------------------------
// Pre-pass: x fp32 -> fp16, permuted within each 8 along K.
// ---------------------------------------------------------------------------
__global__ __launch_bounds__(256) void convert_x_kernel(
    const float* __restrict__ x, f16* __restrict__ xp)
{
    size_t i = ((size_t)blockIdx.x * 256 + threadIdx.x) * 8;
    float4 f0 = *(const float4*)(x + i);
    float4 f1 = *(const float4*)(x + i + 4);
    f16x8 v;
    v[0] = (f16)f0.x; v[1] = (f16)f1.x;
    v[2] = (f16)f0.y; v[3] = (f16)f1.y;
    v[4] = (f16)f0.z; v[5] = (f16)f1.z;
    v[6] = (f16)f0.w; v[7] = (f16)f1.w;
    *(f16x8*)(xp + i) = v;
}

// ---------------------------------------------------------------------------
// Pre-pass: dequant gate+up -> Wg', Wu' as (NN, K) fp16 rows of K (B^T form).
// grid (NN/256, K/32); thread handles one n, one 32-k slab.
// ---------------------------------------------------------------------------
__global__ __launch_bounds__(256) void dequant_gu_kernel(
    const int* __restrict__ gqw, const float* __restrict__ gsc, const int* __restrict__ gqz,
    const int* __restrict__ uqw, const float* __restrict__ usc, const int* __restrict__ uqz,
    f16* __restrict__ wg, f16* __restrict__ wu)
{
    int n  = blockIdx.x * 256 + threadIdx.x;
    int k0 = blockIdx.y * 32;
    int g  = k0 >> 7;
    int sh = (n & 7) * 4;

    float sgf = gsc[(size_t)g * NN + n];
    float suf = usc[(size_t)g * NN + n];
    int zg = (gqz[(size_t)g * (NN / 8) + (n >> 3)] >> sh) & 15;
    int zu = (uqz[(size_t)g * (NN / 8) + (n >> 3)] >> sh) & 15;
    f16 sgh = (f16)sgf, suh = (f16)suf;
    f16 zcg = (f16)(float)(1025 + zg);
    f16 zcu = (f16)(float)(1025 + zu);
    f16x2 s2g = {sgh, sgh}, zc2g = {zcg, zcg};
    f16x2 s2u = {suh, suh}, zc2u = {zcu, zcu};

#pragma unroll
    for (int i = 0; i < 4; ++i) {
        unsigned qg = (unsigned)gqw[(size_t)(k0 / 8 + i) * NN + n];
        unsigned qu = (unsigned)uqw[(size_t)(k0 / 8 + i) * NN + n];
        *(f16x8*)&wg[(size_t)n * K + k0 + i * 8] = dq8(qg, s2g, zc2g);
        *(f16x8*)&wu[(size_t)n * K + k0 + i * 8] = dq8(qu, s2u, zc2u);
    }
}

// ---------------------------------------------------------------------------
// Pre-pass: dequant down -> Wd' as (K, NN) fp16 rows of NN.
// grid (K/256, NN/32); thread handles one c, one 32-n slab.
// ---------------------------------------------------------------------------
__global__ __launch_bounds__(256) void dequant_d_kernel(
    const int* __restrict__ dqw, const float* __restrict__ dsc, const int* __restrict__ dqz,
    f16* __restrict__ wd)
{
    int c  = blockIdx.x * 256 + threadIdx.x;
    int n0 = blockIdx.y * 32;
    int g  = n0 >> 7;
    int sh = (c & 7) * 4;

    float sf = dsc[(size_t)g * K + c];
    int   z  = (dqz[(size_t)g * (K / 8) + (c >> 3)] >> sh) & 15;
    f16 shh = (f16)sf;
    f16 zch = (f16)(float)(1025 + z);
    f16x2 s2 = {shh, shh}, zc2 = {zch, zch};

#pragma unroll
    for (int i = 0; i < 4; ++i) {
        unsigned q = (unsigned)dqw[(size_t)(n0 / 8 + i) * K + c];
        *(f16x8*)&wd[(size_t)c * NN + n0 + i * 8] = dq8(q, s2, zc2);
    }
}

// ---------------------------------------------------------------------------
// Main kernel 1 (fast path): h = silu(xp @ Wg'^T) * (xp @ Wu'^T).
// 128(M) x 64(N) tile, BK=32, all staging via global_load_lds width 16.
// 4 waves 2x2; wave tile 64x32 -> acc[4][2] per matrix (64 VGPR total acc).
// grid (M/128, NN/64): x = m-block so the 1 MB B-strip stays L2-hot.
// ---------------------------------------------------------------------------
__global__ __launch_bounds__(256, 3) void gateup2_kernel(
    const f16* __restrict__ xp,   // (M, K)
    const f16* __restrict__ wg,   // (NN, K)
    const f16* __restrict__ wu,   // (NN, K)
    f16*       __restrict__ h)    // (M, NN) permuted within 8 along NN
{
    __shared__ __align__(16) f16 AS[128 * 32];   // 8 KB
    __shared__ __align__(16) f16 BGS[64 * 32];   // 4 KB
    __shared__ __align__(16) f16 BUS[64 * 32];   // 4 KB

    const int tid    = threadIdx.x;
    const int m_base = blockIdx.x * 128;
    const int n_base = blockIdx.y * 64;

    const int lane = tid & 63;
    const int wave = tid >> 6;
    const int wm   = (wave >> 1) * 64;
    const int wn   = (wave & 1) * 32;
    const int quad = lane >> 4;
    const int lr   = lane & 15;

    // staging addresses (element offsets, +k0 each iter)
    const size_t a0 = (size_t)m_base * K + swz_dec(wave * 128 + lane, K);
    const size_t a1 = (size_t)m_base * K + swz_dec(wave * 128 + 64 + lane, K);
    const int wb = wave & 1;
    const size_t b0 = (size_t)n_base * K + swz_dec(wb * 128 + lane, K);
    const size_t b1 = (size_t)n_base * K + swz_dec(wb * 128 + 64 + lane, K);
    const f16* bsrc = (wave < 2) ? wg : wu;
    f16* bdst = (wave < 2) ? BGS : BUS;

    // fragment LDS offsets
    int offA[4], offB[2];
#pragma unroll
    for (int t = 0; t < 4; ++t) offA[t] = swz_read(wm + t * 16 + lr, quad);
#pragma unroll
    for (int t = 0; t < 2; ++t) offB[t] = swz_read(wn + t * 16 + lr, quad);

    f32x4 accg[4][2], accu[4][2];
#pragma unroll
    for (int i = 0; i < 4; ++i)
#pragma unroll
        for (int j = 0; j < 2; ++j) {
            accg[i][j] = (f32x4){0.f, 0.f, 0.f, 0.f};
            accu[i][j] = (f32x4){0.f, 0.f, 0.f, 0.f};
        }

    for (int k0 = 0; k0 < K; k0 += 32) {
        gll16(xp + a0 + k0, &AS[wave * 1024]);
        gll16(xp + a1 + k0, &AS[wave * 1024 + 512]);
        gll16(bsrc + b0 + k0, bdst + wb * 1024);
        gll16(bsrc + b1 + k0, bdst + wb * 1024 + 512);

        __syncthreads();

        f16x8 af[4];
#pragma unroll
        for (int t = 0; t < 4; ++t) af[t] = *(const f16x8*)&AS[offA[t]];

#pragma unroll
        for (int nt = 0; nt < 2; ++nt) {
            f16x8 bg = *(const f16x8*)&BGS[offB[nt]];
#pragma unroll
            for (int mt = 0; mt < 4; ++mt)
                accg[mt][nt] = __builtin_amdgcn_mfma_f32_16x16x32_f16(af[mt], bg, accg[mt][nt], 0, 0, 0);
            f16x8 bu = *(const f16x8*)&BUS[offB[nt]];
#pragma unroll
            for (int mt = 0; mt < 4; ++mt)
                accu[mt][nt] = __builtin_amdgcn_mfma_f32_16x16x32_f16(af[mt], bu, accu[mt][nt], 0, 0, 0);
        }

        __syncthreads();
    }

    // epilogue: silu(g)*u -> h fp16, columns permuted within 8 along NN
#pragma unroll
    for (int mt = 0; mt < 4; ++mt)
#pragma unroll
        for (int nt = 0; nt < 2; ++nt)
#pragma unroll
            for (int r = 0; r < 4; ++r) {
                int m = m_base + wm + mt * 16 + quad * 4 + r;
                int n = n_base + wn + nt * 16 + lr;
                int np = (n & ~7) | (((n & 3) << 1) | ((n >> 2) & 1));
                float gv = accg[mt][nt][r];
                float uv = accu[mt][nt][r];
                float hv = (gv / (1.0f + __expf(-gv))) * uv;
                h[(size_t)m * NN + np] = (f16)hv;
            }
}

// ---------------------------------------------------------------------------
// Main kernel 2 (fast path): out = h @ Wd'^T. 128x128 tile, BK=32,
// global_load_lds staging, acc[4][4] (64 VGPR). grid (M/128, K/128).
// ---------------------------------------------------------------------------
__global__ __launch_bounds__(256, 3) void down2_kernel(
    const f16*  __restrict__ h,    // (M, NN) permuted within 8
    const f16*  __restrict__ wd,   // (K, NN) permuted within 8
    float*      __restrict__ out)  // (M, K) fp32
{
    __shared__ __align__(16) f16 AS[128 * 32];   // 8 KB
    __shared__ __align__(16) f16 BS[128 * 32];   // 8 KB

    const int tid    = threadIdx.x;
    const int m_base = blockIdx.x * 128;
    const int c_base = blockIdx.y * 128;

    const int lane = tid & 63;
    const int wave = tid >> 6;
    const int wm   = (wave >> 1) * 64;
    const int wn   = (wave & 1) * 64;
    const int quad = lane >> 4;
    const int lr   = lane & 15;

    const size_t a0 = (size_t)m_base * NN + swz_dec(wave * 128 + lane, NN);
    const size_t a1 = (size_t)m_base * NN + swz_dec(wave * 128 + 64 + lane, NN);
    const size_t b0 = (size_t)c_base * NN + swz_dec(wave * 128 + lane, NN);
    const size_t b1 = (size_t)c_base * NN + swz_dec(wave * 128 + 64 + lane, NN);

    int offA[4], offB[4];
#pragma unroll
    for (int t = 0; t < 4; ++t) offA[t] = swz_read(wm + t * 16 + lr, quad);
#pragma unroll
    for (int t = 0; t < 4; ++t) offB[t] = swz_read(wn + t * 16 + lr, quad);

    f32x4 acc[4][4];
#pragma unroll
    for (int i = 0; i < 4; ++i)
#pragma unroll
        for (int j = 0; j < 4; ++j) acc[i][j] = (f32x4){0.f, 0.f, 0.f, 0.f};

    for (int n0 = 0; n0 < NN; n0 += 32) {
        gll16(h + a0 + n0, &AS[wave * 1024]);
        gll16(h + a1 + n0, &AS[wave * 1024 + 512]);
        gll16(wd + b0 + n0, &BS[wave * 1024]);
        gll16(wd + b1 + n0, &BS[wave * 1024 + 512]);

        __syncthreads();

        f16x8 af[4];
#pragma unroll
        for (int t = 0; t < 4; ++t) af[t] = *(const f16x8*)&AS[offA[t]];

#pragma unroll
        for (int nt = 0; nt < 4; ++nt) {
            f16x8 b = *(const f16x8*)&BS[offB[nt]];
#pragma unroll
            for (int mt = 0; mt < 4; ++mt)
                acc[mt][nt] = __builtin_amdgcn_mfma_f32_16x16x32_f16(af[mt], b, acc[mt][nt], 0, 0, 0);
        }

        __syncthreads();
    }

#pragma unroll
    for (int mt = 0; mt < 4; ++mt)
#pragma unroll
        for (int nt = 0; nt < 4; ++nt)
#pragma unroll
            for (int r = 0; r < 4; ++r) {
                int m = m_base + wm + mt * 16 + quad * 4 + r;
                int c = c_base + wn + nt * 16 + lr;
                out[(size_t)m * K + c] = acc[mt][nt][r];
            }
}

// ===========================================================================
// Fallback path (round-3 kernels, known-passing): used if ws_size < 304 MB.
// ===========================================================================
static constexpr int LDK = 40;

__global__ __launch_bounds__(256) void gateup_fb_kernel(
    const f16* __restrict__ xp, const int* __restrict__ gqw,
    const float* __restrict__ gsc, const int* __restrict__ gqz,
    const int* __restrict__ uqw, const float* __restrict__ usc,
    const int* __restrict__ uqz, f16* __restrict__ h)
{
    __shared__ f16 As[128][LDK];
    __shared__ f16 Bg[128][LDK];
    __shared__ f16 Bu[128][LDK];

    const int tid    = threadIdx.x;
    const int m_base = blockIdx.y * 128;
    const int n_base = blockIdx.x * 128;
    const int lane = tid & 63;
    const int wave = tid >> 6;
    const int wm   = (wave >> 1) * 64;
    const int wn   = (wave & 1) * 64;
    const int quad = lane >> 4;
    const int lr   = lane & 15;

    f32x4 accg[4][4], accu[4][4];
#pragma unroll
    for (int i = 0; i < 4; ++i)
#pragma unroll
        for (int j = 0; j < 4; ++j) {
            accg[i][j] = (f32x4){0.f, 0.f, 0.f, 0.f};
            accu[i][j] = (f32x4){0.f, 0.f, 0.f, 0.f};
        }

    const int nn  = tid & 127;
    const int kr0 = tid >> 7;
    const int gn  = n_base + nn;
    const int sh  = (nn & 7) * 4;
    const int am  = tid >> 2;
    const int ac  = tid & 3;

    for (int g = 0; g < 32; ++g) {
        float sgf = gsc[(size_t)g * NN + gn];
        float suf = usc[(size_t)g * NN + gn];
        int zg = (gqz[(size_t)g * (NN / 8) + (gn >> 3)] >> sh) & 15;
        int zu = (uqz[(size_t)g * (NN / 8) + (gn >> 3)] >> sh) & 15;
        f16 sgh = (f16)sgf, suh = (f16)suf;
        f16 zcg = (f16)(float)(1025 + zg);
        f16 zcu = (f16)(float)(1025 + zu);
        f16x2 s2g = {sgh, sgh}, zc2g = {zcg, zcg};
        f16x2 s2u = {suh, suh}, zc2u = {zcu, zcu};

        for (int kk = 0; kk < 4; ++kk) {
            const int k0 = g * 128 + kk * 32;
#pragma unroll
            for (int r = 0; r < 2; ++r) {
                int m = r * 64 + am;
                f16x8 v = *(const f16x8*)(xp + (size_t)(m_base + m) * K + k0 + ac * 8);
                *(f16x8*)&As[m][((ac + m) & 3) * 8] = v;
            }
#pragma unroll
            for (int rr = 0; rr < 2; ++rr) {
                int kr = kr0 + rr * 2;
                unsigned qg = (unsigned)gqw[(size_t)(k0 / 8 + kr) * NN + gn];
                unsigned qu = (unsigned)uqw[(size_t)(k0 / 8 + kr) * NN + gn];
                *(f16x8*)&Bg[nn][((kr + nn) & 3) * 8] = dq8(qg, s2g, zc2g);
                *(f16x8*)&Bu[nn][((kr + nn) & 3) * 8] = dq8(qu, s2u, zc2u);
            }
            __syncthreads();

            f16x8 af[4], bg[4], bu[4];
#pragma unroll
            for (int t = 0; t < 4; ++t) {
                int row = wm + t * 16 + lr;
                af[t] = *(const f16x8*)&As[row][((quad + row) & 3) * 8];
            }
#pragma unroll
            for (int t = 0; t < 4; ++t) {
                int row = wn + t * 16 + lr;
                bg[t] = *(const f16x8*)&Bg[row][((quad + row) & 3) * 8];
                bu[t] = *(const f16x8*)&Bu[row][((quad + row) & 3) * 8];
            }
#pragma unroll
            for (int mt = 0; mt < 4; ++mt)
#pragma unroll
                for (int nt = 0; nt < 4; ++nt) {
                    accg[mt][nt] = __builtin_amdgcn_mfma_f32_16x16x32_f16(af[mt], bg[nt], accg[mt][nt], 0, 0, 0);
                    accu[mt][nt] = __builtin_amdgcn_mfma_f32_16x16x32_f16(af[mt], bu[nt], accu[mt][nt], 0, 0, 0);
                }
            __syncthreads();
        }
    }
#pragma unroll
    for (int mt = 0; mt < 4; ++mt)
#pragma unroll
        for (int nt = 0; nt < 4; ++nt)
#pragma unroll
            for (int r = 0; r < 4; ++r) {
                int m = m_base + wm + mt * 16 + quad * 4 + r;
                int n = n_base + wn + nt * 16 + lr;
                int np = (n & ~7) | (((n & 3) << 1) | ((n >> 2) & 1));
                float gv = accg[mt][nt][r];
                float uv = accu[mt][nt][r];
                float hv = (gv / (1.0f + __expf(-gv))) * uv;
                h[(size_t)m * NN + np] = (f16)hv;
            }
}

__global__ __launch_bounds__(256) void down_fb_kernel(
    const f16* __restrict__ h, const int* __restrict__ dqw,
    const float* __restrict__ dsc, const int* __restrict__ dqz,
    float* __restrict__ out)
{
    __shared__ f16 As[128][LDK];
    __shared__ f16 Bs[128][LDK];

    const int tid    = threadIdx.x;
    const int m_base = blockIdx.y * 128;
    const int c_base = blockIdx.x * 128;
    const int lane = tid & 63;
    const int wave = tid >> 6;
    const int wm   = (wave >> 1) * 64;
    const int wn   = (wave & 1) * 64;
    const int quad = lane >> 4;
    const int lr   = lane & 15;

    f32x4 acc[4][4];
#pragma unroll
    for (int i = 0; i < 4; ++i)
#pragma unroll
        for (int j = 0; j < 4; ++j) acc[i][j] = (f32x4){0.f, 0.f, 0.f, 0.f};

    const int cc  = tid & 127;
    const int kr0 = tid >> 7;
    const int gc  = c_base + cc;
    const int sh  = (cc & 7) * 4;
    const int am  = tid >> 2;
    const int ac  = tid & 3;

    for (int g = 0; g < 86; ++g) {
        float sf = dsc[(size_t)g * K + gc];
        int   z  = (dqz[(size_t)g * (K / 8) + (gc >> 3)] >> sh) & 15;
        f16 shh = (f16)sf;
        f16 zch = (f16)(float)(1025 + z);
        f16x2 s2 = {shh, shh}, zc2 = {zch, zch};

        for (int kk = 0; kk < 4; ++kk) {
            const int n0 = g * 128 + kk * 32;
#pragma unroll
            for (int r = 0; r < 2; ++r) {
                int m = r * 64 + am;
                f16x8 v = *(const f16x8*)(h + (size_t)(m_base + m) * NN + n0 + ac * 8);
                *(f16x8*)&As[m][((ac + m) & 3) * 8] = v;
            }
#pragma unroll
            for (int rr = 0; rr < 2; ++rr) {
                int kr = kr0 + rr * 2;
                unsigned q = (unsigned)dqw[(size_t)(n0 / 8 + kr) * K + gc];
                *(f16x8*)&Bs[cc][((kr + cc) & 3) * 8] = dq8(q, s2, zc2);
            }
            __syncthreads();

            f16x8 af[4], bf[4];
#pragma unroll
            for (int t = 0; t < 4; ++t) {
                int row = wm + t * 16 + lr;
                af[t] = *(const f16x8*)&As[row][((quad + row) & 3) * 8];
            }
#pragma unroll
            for (int t = 0; t < 4; ++t) {
                int row = wn + t * 16 + lr;
                bf[t] = *(const f16x8*)&Bs[row][((quad + row) & 3) * 8];
            }
#pragma unroll
            for (int mt = 0; mt < 4; ++mt)
#pragma unroll
                for (int nt = 0; nt < 4; ++nt)
                    acc[mt][nt] = __builtin_amdgcn_mfma_f32_16x16x32_f16(af[mt], bf[nt], acc[mt][nt], 0, 0, 0);
            __syncthreads();
        }
    }
#pragma unroll
    for (int mt = 0; mt < 4; ++mt)
#pragma unroll
        for (int nt = 0; nt < 4; ++nt)
#pragma unroll
            for (int r = 0; r < 4; ++r) {
                int m = m_base + wm + mt * 16 + quad * 4 + r;
                int c = c_base + wn + nt * 16 + lr;
                out[(size_t)m * K + c] = acc[mt][nt][r];
            }
}

extern "C" void kernel_launch(void* const* d_in, const int* in_sizes, int n_in,
                              void* d_out, int out_size, void* d_ws, size_t ws_size,
                              hipStream_t stream) {
    const float* x   = (const float*)d_in[0];
    const int*   gqw = (const int*)d_in[1];
    const float* gsc = (const float*)d_in[2];
    const int*   gqz = (const int*)d_in[3];
    const int*   uqw = (const int*)d_in[4];
    const float* usc = (const float*)d_in[5];
    const int*   uqz = (const int*)d_in[6];
    const int*   dqw = (const int*)d_in[7];
    const float* dsc = (const float*)d_in[8];
    const int*   dqz = (const int*)d_in[9];
    float* out = (float*)d_out;

    const size_t HB = (size_t)M * NN * 2;   // 90,177,536
    const size_t XB = (size_t)M * K * 2;    // 33,554,432
    const size_t WB = (size_t)K * NN * 2;   // 90,177,536
    const size_t NEED = HB + XB + 2 * WB;   // ~304 MB

    char* ws = (char*)d_ws;
    f16* h  = (f16*)ws;
    f16* xp = (f16*)(ws + HB);

    convert_x_kernel<<<(M * K / 8) / 256, 256, 0, stream>>>(x, xp);

    if (ws_size >= NEED) {
        f16* wg = (f16*)(ws + HB + XB);
        f16* wu = (f16*)(ws + HB + XB + WB);
        f16* wd = wg;   // reuses wg region after gateup2 is done

        dequant_gu_kernel<<<dim3(NN / 256, K / 32), 256, 0, stream>>>(
            gqw, gsc, gqz, uqw, usc, uqz, wg, wu);

        gateup2_kernel<<<dim3(M / 128, NN / 64), 256, 0, stream>>>(xp, wg, wu, h);

        dequant_d_kernel<<<dim3(K / 256, NN / 32), 256, 0, stream>>>(dqw, dsc, dqz, wd);

        down2_kernel<<<dim3(M / 128, K / 128), 256, 0, stream>>>(h, wd, out);
    } else {
        gateup_fb_kernel<<<dim3(NN / 128, M / 128), 256, 0, stream>>>(
            xp, gqw, gsc, gqz, uqw, usc, uqz, h);
        down_fb_kernel<<<dim3(K / 128, M / 128), 256, 0, stream>>>(h, dqw, dsc, dqz, out);
    }
}

// Round 5
// 1667.560 us; speedup vs baseline: 1.4347x; 1.4347x over previous
//
#include <hip/hip_runtime.h>
#include <hip/hip_bf16.h>

// B=2, S=2048 -> M=4096 tokens, K=4096, NN=11008, groupsize=128.
static constexpr int M  = 4096;
static constexpr int K  = 4096;
static constexpr int NN = 11008;

typedef _Float16 f16;
typedef _Float16 f16x2 __attribute__((ext_vector_type(2)));
typedef _Float16 f16x8 __attribute__((ext_vector_type(8)));
typedef float    f32x4 __attribute__((ext_vector_type(4)));

// ---------------------------------------------------------------------------
// GPTQ nibble j of an int32 covers k = 8r+j. The magic unpack emits the
// interleaved within-8 order [0,4,1,5,2,6,3,7]; all fp16 tensors (xp, Wg',
// Wu', Wd', h) use this same permutation along their reduction dim.
// Numerics: (1024+w) and (1025+z) are exact fp16 integers; their difference
// is exact; single rounding at the final mul by s (round 3: absmax 16).
// ---------------------------------------------------------------------------
union dq_u { f16x2 h[4]; f16x8 v; };

__device__ __forceinline__ f16x8 dq8(unsigned q, f16x2 s2, f16x2 zc2) {
    dq_u u;
    unsigned t0 = ( q         & 0x000F000Fu) | 0x64006400u;
    unsigned t1 = ((q >> 4)   & 0x000F000Fu) | 0x64006400u;
    unsigned t2 = ((q >> 8)   & 0x000F000Fu) | 0x64006400u;
    unsigned t3 = ((q >> 12)  & 0x000F000Fu) | 0x64006400u;
    u.h[0] = (__builtin_bit_cast(f16x2, t0) - zc2) * s2;
    u.h[1] = (__builtin_bit_cast(f16x2, t1) - zc2) * s2;
    u.h[2] = (__builtin_bit_cast(f16x2, t2) - zc2) * s2;
    u.h[3] = (__builtin_bit_cast(f16x2, t3) - zc2) * s2;
    return u.v;
}

// async global -> LDS, 16 B/lane; LDS dest = wave-uniform base + lane*16.
__device__ __forceinline__ void gll16(const f16* g, f16* l) {
    __builtin_amdgcn_global_load_lds(
        (const __attribute__((address_space(1))) unsigned int*)g,
        (__attribute__((address_space(3))) unsigned int*)l,
        16, 0, 0);
}

// Bank swizzle for R x 32-half tiles (4 chunks of 16B per row).
// Slot s (= staging lane order) holds global chunk c of row r = s>>2 where
// (c + p(r)) & 3 == (s & 3), p(r) = (r ^ (r>>2)) & 3.
// Enumerated: every 16-lane quad phase of a fragment ds_read_b128 is exactly
// 2-way per bank group -> free (m136). Staging writes are HW lane*16.
__device__ __forceinline__ int swz_p(int r) { return (r ^ (r >> 2)) & 3; }

__device__ __forceinline__ size_t swz_dec(int s, int ld) {
    int r  = s >> 2;
    int c  = ((s & 3) - swz_p(r)) & 3;
    return (size_t)r * ld + c * 8;
}

__device__ __forceinline__ int swz_read(int row, int q) {
    return (row * 4 + ((q + swz_p(row)) & 3)) * 8;
}

// ---------------------------------------------------------------------------
// Pre-pass: x fp32 -> fp16, permuted within each 8 along K.
// ---------------------------------------------------------------------------
__global__ __launch_bounds__(256) void convert_x_kernel(
    const float* __restrict__ x, f16* __restrict__ xp)
{
    size_t i = ((size_t)blockIdx.x * 256 + threadIdx.x) * 8;
    float4 f0 = *(const float4*)(x + i);
    float4 f1 = *(const float4*)(x + i + 4);
    f16x8 v;
    v[0] = (f16)f0.x; v[1] = (f16)f1.x;
    v[2] = (f16)f0.y; v[3] = (f16)f1.y;
    v[4] = (f16)f0.z; v[5] = (f16)f1.z;
    v[6] = (f16)f0.w; v[7] = (f16)f1.w;
    *(f16x8*)(xp + i) = v;
}

// ---------------------------------------------------------------------------
// Dequant strip: gate+up columns [n0, n0+NC) -> wg/wu as (NC, K) fp16.
// grid (NC/256, K/32); each thread writes one full 64B line.
// ---------------------------------------------------------------------------
__global__ __launch_bounds__(256) void dequant_gu_strip(
    const int* __restrict__ gqw, const float* __restrict__ gsc, const int* __restrict__ gqz,
    const int* __restrict__ uqw, const float* __restrict__ usc, const int* __restrict__ uqz,
    f16* __restrict__ wg, f16* __restrict__ wu, int n0)
{
    int nl = blockIdx.x * 256 + threadIdx.x;   // strip-local column
    int n  = n0 + nl;                          // global column
    int k0 = blockIdx.y * 32;
    int g  = k0 >> 7;
    int sh = (n & 7) * 4;

    float sgf = gsc[(size_t)g * NN + n];
    float suf = usc[(size_t)g * NN + n];
    int zg = (gqz[(size_t)g * (NN / 8) + (n >> 3)] >> sh) & 15;
    int zu = (uqz[(size_t)g * (NN / 8) + (n >> 3)] >> sh) & 15;
    f16 sgh = (f16)sgf, suh = (f16)suf;
    f16 zcg = (f16)(float)(1025 + zg);
    f16 zcu = (f16)(float)(1025 + zu);
    f16x2 s2g = {sgh, sgh}, zc2g = {zcg, zcg};
    f16x2 s2u = {suh, suh}, zc2u = {zcu, zcu};

#pragma unroll
    for (int i = 0; i < 4; ++i) {
        unsigned qg = (unsigned)gqw[(size_t)(k0 / 8 + i) * NN + n];
        unsigned qu = (unsigned)uqw[(size_t)(k0 / 8 + i) * NN + n];
        *(f16x8*)&wg[(size_t)nl * K + k0 + i * 8] = dq8(qg, s2g, zc2g);
        *(f16x8*)&wu[(size_t)nl * K + k0 + i * 8] = dq8(qu, s2u, zc2u);
    }
}

// ---------------------------------------------------------------------------
// Dequant strip: down output columns [c0, c0+KC) -> wd as (KC, NN) fp16.
// grid (KC/256, NN/32).
// ---------------------------------------------------------------------------
__global__ __launch_bounds__(256) void dequant_d_strip(
    const int* __restrict__ dqw, const float* __restrict__ dsc, const int* __restrict__ dqz,
    f16* __restrict__ wd, int c0)
{
    int cl = blockIdx.x * 256 + threadIdx.x;
    int c  = c0 + cl;
    int n0 = blockIdx.y * 32;
    int g  = n0 >> 7;
    int sh = (c & 7) * 4;

    float sf = dsc[(size_t)g * K + c];
    int   z  = (dqz[(size_t)g * (K / 8) + (c >> 3)] >> sh) & 15;
    f16 shh = (f16)sf;
    f16 zch = (f16)(float)(1025 + z);
    f16x2 s2 = {shh, shh}, zc2 = {zch, zch};

#pragma unroll
    for (int i = 0; i < 4; ++i) {
        unsigned q = (unsigned)dqw[(size_t)(n0 / 8 + i) * K + c];
        *(f16x8*)&wd[(size_t)cl * NN + n0 + i * 8] = dq8(q, s2, zc2);
    }
}

// ---------------------------------------------------------------------------
// GEMM 1: h[:, n0+...] = silu(xp @ Wg'^T) * (xp @ Wu'^T) over one strip.
// 128(M) x 64(N) tile, BK=32, all staging via global_load_lds width 16.
// 4 waves 2x2; per-wave 64x32 per matrix -> acc[4][2] x2 (64 VGPR acc).
// grid (M/128, NC/64): x = m fastest so the B-strip stays L2-hot.
// ---------------------------------------------------------------------------
__global__ __launch_bounds__(256, 3) void gateup2_kernel(
    const f16* __restrict__ xp,   // (M, K)
    const f16* __restrict__ wg,   // (NC, K) strip-local
    const f16* __restrict__ wu,   // (NC, K) strip-local
    f16*       __restrict__ h,    // (M, NN) permuted within 8 along NN
    int n0)
{
    __shared__ __align__(16) f16 AS[128 * 32];   // 8 KB
    __shared__ __align__(16) f16 BGS[64 * 32];   // 4 KB
    __shared__ __align__(16) f16 BUS[64 * 32];   // 4 KB

    const int tid     = threadIdx.x;
    const int m_base  = blockIdx.x * 128;
    const int nl_base = blockIdx.y * 64;         // strip-local

    const int lane = tid & 63;
    const int wave = tid >> 6;
    const int wm   = (wave >> 1) * 64;
    const int wn   = (wave & 1) * 32;
    const int quad = lane >> 4;
    const int lr   = lane & 15;

    const size_t a0 = (size_t)m_base * K + swz_dec(wave * 128 + lane, K);
    const size_t a1 = (size_t)m_base * K + swz_dec(wave * 128 + 64 + lane, K);
    const int wb = wave & 1;
    const size_t b0 = (size_t)nl_base * K + swz_dec(wb * 128 + lane, K);
    const size_t b1 = (size_t)nl_base * K + swz_dec(wb * 128 + 64 + lane, K);
    const f16* bsrc = (wave < 2) ? wg : wu;
    f16* bdst = (wave < 2) ? BGS : BUS;

    int offA[4], offB[2];
#pragma unroll
    for (int t = 0; t < 4; ++t) offA[t] = swz_read(wm + t * 16 + lr, quad);
#pragma unroll
    for (int t = 0; t < 2; ++t) offB[t] = swz_read(wn + t * 16 + lr, quad);

    f32x4 accg[4][2], accu[4][2];
#pragma unroll
    for (int i = 0; i < 4; ++i)
#pragma unroll
        for (int j = 0; j < 2; ++j) {
            accg[i][j] = (f32x4){0.f, 0.f, 0.f, 0.f};
            accu[i][j] = (f32x4){0.f, 0.f, 0.f, 0.f};
        }

    for (int k0 = 0; k0 < K; k0 += 32) {
        gll16(xp + a0 + k0, &AS[wave * 1024]);
        gll16(xp + a1 + k0, &AS[wave * 1024 + 512]);
        gll16(bsrc + b0 + k0, bdst + wb * 1024);
        gll16(bsrc + b1 + k0, bdst + wb * 1024 + 512);

        __syncthreads();

        f16x8 af[4];
#pragma unroll
        for (int t = 0; t < 4; ++t) af[t] = *(const f16x8*)&AS[offA[t]];

#pragma unroll
        for (int nt = 0; nt < 2; ++nt) {
            f16x8 bg = *(const f16x8*)&BGS[offB[nt]];
#pragma unroll
            for (int mt = 0; mt < 4; ++mt)
                accg[mt][nt] = __builtin_amdgcn_mfma_f32_16x16x32_f16(af[mt], bg, accg[mt][nt], 0, 0, 0);
            f16x8 bu = *(const f16x8*)&BUS[offB[nt]];
#pragma unroll
            for (int mt = 0; mt < 4; ++mt)
                accu[mt][nt] = __builtin_amdgcn_mfma_f32_16x16x32_f16(af[mt], bu, accu[mt][nt], 0, 0, 0);
        }

        __syncthreads();
    }

    // epilogue: silu(g)*u -> h fp16, global columns permuted within 8
#pragma unroll
    for (int mt = 0; mt < 4; ++mt)
#pragma unroll
        for (int nt = 0; nt < 2; ++nt)
#pragma unroll
            for (int r = 0; r < 4; ++r) {
                int m = m_base + wm + mt * 16 + quad * 4 + r;
                int n = n0 + nl_base + wn + nt * 16 + lr;
                int np = (n & ~7) | (((n & 3) << 1) | ((n >> 2) & 1));
                float gv = accg[mt][nt][r];
                float uv = accu[mt][nt][r];
                float hv = (gv / (1.0f + __expf(-gv))) * uv;
                h[(size_t)m * NN + np] = (f16)hv;
            }
}

// ---------------------------------------------------------------------------
// GEMM 2: out[:, c0+...] = h @ Wd'^T over one strip. 128x128 tile, BK=32,
// global_load_lds staging, acc[4][4]. grid (M/128, KC/128).
// ---------------------------------------------------------------------------
__global__ __launch_bounds__(256, 3) void down2_kernel(
    const f16*  __restrict__ h,    // (M, NN) permuted within 8
    const f16*  __restrict__ wd,   // (KC, NN) strip-local, permuted within 8
    float*      __restrict__ out,  // (M, K) fp32
    int c0)
{
    __shared__ __align__(16) f16 AS[128 * 32];   // 8 KB
    __shared__ __align__(16) f16 BS[128 * 32];   // 8 KB

    const int tid     = threadIdx.x;
    const int m_base  = blockIdx.x * 128;
    const int cl_base = blockIdx.y * 128;        // strip-local

    const int lane = tid & 63;
    const int wave = tid >> 6;
    const int wm   = (wave >> 1) * 64;
    const int wn   = (wave & 1) * 64;
    const int quad = lane >> 4;
    const int lr   = lane & 15;

    const size_t a0 = (size_t)m_base * NN + swz_dec(wave * 128 + lane, NN);
    const size_t a1 = (size_t)m_base * NN + swz_dec(wave * 128 + 64 + lane, NN);
    const size_t b0 = (size_t)cl_base * NN + swz_dec(wave * 128 + lane, NN);
    const size_t b1 = (size_t)cl_base * NN + swz_dec(wave * 128 + 64 + lane, NN);

    int offA[4], offB[4];
#pragma unroll
    for (int t = 0; t < 4; ++t) offA[t] = swz_read(wm + t * 16 + lr, quad);
#pragma unroll
    for (int t = 0; t < 4; ++t) offB[t] = swz_read(wn + t * 16 + lr, quad);

    f32x4 acc[4][4];
#pragma unroll
    for (int i = 0; i < 4; ++i)
#pragma unroll
        for (int j = 0; j < 4; ++j) acc[i][j] = (f32x4){0.f, 0.f, 0.f, 0.f};

    for (int nn0 = 0; nn0 < NN; nn0 += 32) {
        gll16(h + a0 + nn0, &AS[wave * 1024]);
        gll16(h + a1 + nn0, &AS[wave * 1024 + 512]);
        gll16(wd + b0 + nn0, &BS[wave * 1024]);
        gll16(wd + b1 + nn0, &BS[wave * 1024 + 512]);

        __syncthreads();

        f16x8 af[4];
#pragma unroll
        for (int t = 0; t < 4; ++t) af[t] = *(const f16x8*)&AS[offA[t]];

#pragma unroll
        for (int nt = 0; nt < 4; ++nt) {
            f16x8 b = *(const f16x8*)&BS[offB[nt]];
#pragma unroll
            for (int mt = 0; mt < 4; ++mt)
                acc[mt][nt] = __builtin_amdgcn_mfma_f32_16x16x32_f16(af[mt], b, acc[mt][nt], 0, 0, 0);
        }

        __syncthreads();
    }

#pragma unroll
    for (int mt = 0; mt < 4; ++mt)
#pragma unroll
        for (int nt = 0; nt < 4; ++nt)
#pragma unroll
            for (int r = 0; r < 4; ++r) {
                int m = m_base + wm + mt * 16 + quad * 4 + r;
                int c = c0 + cl_base + wn + nt * 16 + lr;
                out[(size_t)m * K + c] = acc[mt][nt][r];
            }
}

extern "C" void kernel_launch(void* const* d_in, const int* in_sizes, int n_in,
                              void* d_out, int out_size, void* d_ws, size_t ws_size,
                              hipStream_t stream) {
    const float* x   = (const float*)d_in[0];
    const int*   gqw = (const int*)d_in[1];
    const float* gsc = (const float*)d_in[2];
    const int*   gqz = (const int*)d_in[3];
    const int*   uqw = (const int*)d_in[4];
    const float* usc = (const float*)d_in[5];
    const int*   uqz = (const int*)d_in[6];
    const int*   dqw = (const int*)d_in[7];
    const float* dsc = (const float*)d_in[8];
    const int*   dqz = (const int*)d_in[9];
    float* out = (float*)d_out;

    const size_t HB = (size_t)M * NN * 2;   // h:  90,177,536 B
    char* ws = (char*)d_ws;
    f16* h  = (f16*)ws;
    f16* xp = (f16*)(ws + HB);              // +33,554,432 B (round 3 proved fit)

    convert_x_kernel<<<(M * K / 8) / 256, 256, 0, stream>>>(x, xp);

    // ---- gate/up: weight strips live in d_out (free until down2 runs).
    // d_out = M*K*4 = 67,108,864 B = exactly 4096 columns * (Wg'+Wu') @16KB.
    const int NCg = 4096;
    for (int n0 = 0; n0 < NN; n0 += NCg) {
        int nc = NN - n0 < NCg ? NN - n0 : NCg;   // 4096, 4096, 2816
        f16* wg = (f16*)d_out;
        f16* wu = wg + (size_t)nc * K;
        dequant_gu_strip<<<dim3(nc / 256, K / 32), 256, 0, stream>>>(
            gqw, gsc, gqz, uqw, usc, uqz, wg, wu, n0);
        gateup2_kernel<<<dim3(M / 128, nc / 64), 256, 0, stream>>>(xp, wg, wu, h, n0);
    }

    // ---- down: weight strips reuse xp region (dead) + any spare ws tail.
    size_t availD = ws_size - HB;                   // >= 33.5 MB guaranteed
    int KC = (int)(availD / ((size_t)NN * 2));
    KC &= ~255;                                     // multiple of 256
    if (KC > K) KC = K;
    if (KC < 256) KC = 256;                         // unreachable guard
    f16* wd = (f16*)(ws + HB);
    for (int c0 = 0; c0 < K; c0 += KC) {
        int kc = K - c0 < KC ? K - c0 : KC;         // multiples of 256
        dequant_d_strip<<<dim3(kc / 256, NN / 32), 256, 0, stream>>>(
            dqw, dsc, dqz, wd, c0);
        down2_kernel<<<dim3(M / 128, kc / 128), 256, 0, stream>>>(h, wd, out, c0);
    }
}

// Round 6
// 1574.112 us; speedup vs baseline: 1.5199x; 1.0594x over previous
//
#include <hip/hip_runtime.h>
#include <hip/hip_bf16.h>

// B=2, S=2048 -> M=4096 tokens, K=4096, NN=11008, groupsize=128.
static constexpr int M  = 4096;
static constexpr int K  = 4096;
static constexpr int NN = 11008;

typedef _Float16 f16;
typedef _Float16 f16x2 __attribute__((ext_vector_type(2)));
typedef _Float16 f16x8 __attribute__((ext_vector_type(8)));
typedef float    f32x4 __attribute__((ext_vector_type(4)));

// ---------------------------------------------------------------------------
// GPTQ nibble j of an int32 covers k = 8r+j. The magic unpack emits the
// interleaved within-8 order [0,4,1,5,2,6,3,7]; all fp16 tensors (xp, Wg',
// Wu', Wd', h) use this same permutation along their reduction dim.
// Numerics: (1024+w) and (1025+z) are exact fp16 integers; their difference
// is exact; single rounding at the final mul by s (round 3/5: absmax 16).
// ---------------------------------------------------------------------------
union dq_u { f16x2 h[4]; f16x8 v; };

__device__ __forceinline__ f16x8 dq8(unsigned q, f16x2 s2, f16x2 zc2) {
    dq_u u;
    unsigned t0 = ( q         & 0x000F000Fu) | 0x64006400u;
    unsigned t1 = ((q >> 4)   & 0x000F000Fu) | 0x64006400u;
    unsigned t2 = ((q >> 8)   & 0x000F000Fu) | 0x64006400u;
    unsigned t3 = ((q >> 12)  & 0x000F000Fu) | 0x64006400u;
    u.h[0] = (__builtin_bit_cast(f16x2, t0) - zc2) * s2;
    u.h[1] = (__builtin_bit_cast(f16x2, t1) - zc2) * s2;
    u.h[2] = (__builtin_bit_cast(f16x2, t2) - zc2) * s2;
    u.h[3] = (__builtin_bit_cast(f16x2, t3) - zc2) * s2;
    return u.v;
}

// async global -> LDS, 16 B/lane; LDS dest = wave-uniform base + lane*16.
__device__ __forceinline__ void gll16(const f16* g, f16* l) {
    __builtin_amdgcn_global_load_lds(
        (const __attribute__((address_space(1))) unsigned int*)g,
        (__attribute__((address_space(3))) unsigned int*)l,
        16, 0, 0);
}

// ---------------------------------------------------------------------------
// Pre-pass: x fp32 -> fp16, permuted within each 8 along K.
// ---------------------------------------------------------------------------
__global__ __launch_bounds__(256) void convert_x_kernel(
    const float* __restrict__ x, f16* __restrict__ xp)
{
    size_t i = ((size_t)blockIdx.x * 256 + threadIdx.x) * 8;
    float4 f0 = *(const float4*)(x + i);
    float4 f1 = *(const float4*)(x + i + 4);
    f16x8 v;
    v[0] = (f16)f0.x; v[1] = (f16)f1.x;
    v[2] = (f16)f0.y; v[3] = (f16)f1.y;
    v[4] = (f16)f0.z; v[5] = (f16)f1.z;
    v[6] = (f16)f0.w; v[7] = (f16)f1.w;
    *(f16x8*)(xp + i) = v;
}

// ---------------------------------------------------------------------------
// Dequant strip: gate+up columns [n0, n0+NC) -> wg/wu as (NC, K) fp16.
// grid (NC/256, K/32).
// ---------------------------------------------------------------------------
__global__ __launch_bounds__(256) void dequant_gu_strip(
    const int* __restrict__ gqw, const float* __restrict__ gsc, const int* __restrict__ gqz,
    const int* __restrict__ uqw, const float* __restrict__ usc, const int* __restrict__ uqz,
    f16* __restrict__ wg, f16* __restrict__ wu, int n0)
{
    int nl = blockIdx.x * 256 + threadIdx.x;   // strip-local column
    int n  = n0 + nl;                          // global column
    int k0 = blockIdx.y * 32;
    int g  = k0 >> 7;
    int sh = (n & 7) * 4;

    float sgf = gsc[(size_t)g * NN + n];
    float suf = usc[(size_t)g * NN + n];
    int zg = (gqz[(size_t)g * (NN / 8) + (n >> 3)] >> sh) & 15;
    int zu = (uqz[(size_t)g * (NN / 8) + (n >> 3)] >> sh) & 15;
    f16 sgh = (f16)sgf, suh = (f16)suf;
    f16 zcg = (f16)(float)(1025 + zg);
    f16 zcu = (f16)(float)(1025 + zu);
    f16x2 s2g = {sgh, sgh}, zc2g = {zcg, zcg};
    f16x2 s2u = {suh, suh}, zc2u = {zcu, zcu};

#pragma unroll
    for (int i = 0; i < 4; ++i) {
        unsigned qg = (unsigned)gqw[(size_t)(k0 / 8 + i) * NN + n];
        unsigned qu = (unsigned)uqw[(size_t)(k0 / 8 + i) * NN + n];
        *(f16x8*)&wg[(size_t)nl * K + k0 + i * 8] = dq8(qg, s2g, zc2g);
        *(f16x8*)&wu[(size_t)nl * K + k0 + i * 8] = dq8(qu, s2u, zc2u);
    }
}

// ---------------------------------------------------------------------------
// Dequant strip: down output columns [c0, c0+KC) -> wd as (KC, NN) fp16.
// grid (KC/256, NN/32).
// ---------------------------------------------------------------------------
__global__ __launch_bounds__(256) void dequant_d_strip(
    const int* __restrict__ dqw, const float* __restrict__ dsc, const int* __restrict__ dqz,
    f16* __restrict__ wd, int c0)
{
    int cl = blockIdx.x * 256 + threadIdx.x;
    int c  = c0 + cl;
    int n0 = blockIdx.y * 32;
    int g  = n0 >> 7;
    int sh = (c & 7) * 4;

    float sf = dsc[(size_t)g * K + c];
    int   z  = (dqz[(size_t)g * (K / 8) + (c >> 3)] >> sh) & 15;
    f16 shh = (f16)sf;
    f16 zch = (f16)(float)(1025 + z);
    f16x2 s2 = {shh, shh}, zc2 = {zch, zch};

#pragma unroll
    for (int i = 0; i < 4; ++i) {
        unsigned q = (unsigned)dqw[(size_t)(n0 / 8 + i) * K + c];
        *(f16x8*)&wd[(size_t)cl * NN + n0 + i * 8] = dq8(q, s2, zc2);
    }
}

// ---------------------------------------------------------------------------
// GEMM 1: h[:, n0+...] = silu(xp @ Wg'^T) * (xp @ Wu'^T) over one strip.
// 128(M) x 64(N) tile, BK=64 (two 32-k halves in separate plain LDS
// sub-tiles; 64B row stride = m97 layout, no swizzle). All staging via
// global_load_lds width 16. grid (M/128, NC/64), m fastest (B-strip L2-hot).
// ---------------------------------------------------------------------------
__global__ __launch_bounds__(256, 3) void gateup2_kernel(
    const f16* __restrict__ xp,   // (M, K)
    const f16* __restrict__ wg,   // (NC, K) strip-local
    const f16* __restrict__ wu,   // (NC, K) strip-local
    f16*       __restrict__ h,    // (M, NN) permuted within 8 along NN
    int n0)
{
    __shared__ __align__(16) f16 AS[2][128 * 32];  // 16 KB
    __shared__ __align__(16) f16 BG[2][64 * 32];   //  8 KB
    __shared__ __align__(16) f16 BU[2][64 * 32];   //  8 KB

    const int tid     = threadIdx.x;
    const int m_base  = blockIdx.x * 128;
    const int nl_base = blockIdx.y * 64;          // strip-local

    const int lane = tid & 63;
    const int wave = tid >> 6;
    const int wm   = (wave >> 1) * 64;
    const int wn   = (wave & 1) * 32;
    const int quad = lane >> 4;
    const int lr   = lane & 15;

    const int srow = lane >> 2;   // 0..15 staging row within 16-row group
    const int schk = lane & 3;    // 16B chunk within 64B row segment

    // staging addresses: A rows wave*32+i*16, B rows (wave&1)*32+i*16
    const int bh   = wave & 1;
    const f16* bsrc = (wave < 2) ? wg : wu;
    size_t ag[2][2], bg_[2][2];
    f16 *al[2][2], *bl[2][2];
#pragma unroll
    for (int i = 0; i < 2; ++i)
#pragma unroll
        for (int kh = 0; kh < 2; ++kh) {
            ag[i][kh]  = (size_t)(m_base + wave * 32 + i * 16 + srow) * K + kh * 32 + schk * 8;
            al[i][kh]  = &AS[kh][(wave * 32 + i * 16) * 32];
            bg_[i][kh] = (size_t)(nl_base + bh * 32 + i * 16 + srow) * K + kh * 32 + schk * 8;
            bl[i][kh]  = (wave < 2) ? &BG[kh][(bh * 32 + i * 16) * 32]
                                    : &BU[kh][(bh * 32 + i * 16) * 32];
        }

    f32x4 accg[4][2], accu[4][2];
#pragma unroll
    for (int i = 0; i < 4; ++i)
#pragma unroll
        for (int j = 0; j < 2; ++j) {
            accg[i][j] = (f32x4){0.f, 0.f, 0.f, 0.f};
            accu[i][j] = (f32x4){0.f, 0.f, 0.f, 0.f};
        }

    for (int k0 = 0; k0 < K; k0 += 64) {
#pragma unroll
        for (int i = 0; i < 2; ++i)
#pragma unroll
            for (int kh = 0; kh < 2; ++kh) {
                gll16(xp + ag[i][kh] + k0, al[i][kh]);
                gll16(bsrc + bg_[i][kh] + k0, bl[i][kh]);
            }

        __syncthreads();

#pragma unroll
        for (int kh = 0; kh < 2; ++kh) {
            f16x8 af[4];
#pragma unroll
            for (int t = 0; t < 4; ++t)
                af[t] = *(const f16x8*)&AS[kh][(wm + t * 16 + lr) * 32 + quad * 8];
#pragma unroll
            for (int nt = 0; nt < 2; ++nt) {
                f16x8 vg = *(const f16x8*)&BG[kh][(wn + nt * 16 + lr) * 32 + quad * 8];
#pragma unroll
                for (int mt = 0; mt < 4; ++mt)
                    accg[mt][nt] = __builtin_amdgcn_mfma_f32_16x16x32_f16(af[mt], vg, accg[mt][nt], 0, 0, 0);
                f16x8 vu = *(const f16x8*)&BU[kh][(wn + nt * 16 + lr) * 32 + quad * 8];
#pragma unroll
                for (int mt = 0; mt < 4; ++mt)
                    accu[mt][nt] = __builtin_amdgcn_mfma_f32_16x16x32_f16(af[mt], vu, accu[mt][nt], 0, 0, 0);
            }
        }

        __syncthreads();
    }

    // epilogue: silu(g)*u -> h fp16, global columns permuted within 8
#pragma unroll
    for (int mt = 0; mt < 4; ++mt)
#pragma unroll
        for (int nt = 0; nt < 2; ++nt)
#pragma unroll
            for (int r = 0; r < 4; ++r) {
                int m = m_base + wm + mt * 16 + quad * 4 + r;
                int n = n0 + nl_base + wn + nt * 16 + lr;
                int np = (n & ~7) | (((n & 3) << 1) | ((n >> 2) & 1));
                float gv = accg[mt][nt][r];
                float uv = accu[mt][nt][r];
                float hv = (gv / (1.0f + __expf(-gv))) * uv;
                h[(size_t)m * NN + np] = (f16)hv;
            }
}

// ---------------------------------------------------------------------------
// GEMM 2: out[:, c0+...] = h @ Wd'^T over one strip. 128x128 tile, BK=64,
// plain m97 LDS layout, global_load_lds staging. grid (M/128, KC/128).
// ---------------------------------------------------------------------------
__global__ __launch_bounds__(256, 3) void down2_kernel(
    const f16*  __restrict__ h,    // (M, NN) permuted within 8
    const f16*  __restrict__ wd,   // (KC, NN) strip-local, permuted within 8
    float*      __restrict__ out,  // (M, K) fp32
    int c0)
{
    __shared__ __align__(16) f16 AS[2][128 * 32];  // 16 KB
    __shared__ __align__(16) f16 BS[2][128 * 32];  // 16 KB

    const int tid     = threadIdx.x;
    const int m_base  = blockIdx.x * 128;
    const int cl_base = blockIdx.y * 128;          // strip-local

    const int lane = tid & 63;
    const int wave = tid >> 6;
    const int wm   = (wave >> 1) * 64;
    const int wn   = (wave & 1) * 64;
    const int quad = lane >> 4;
    const int lr   = lane & 15;

    const int srow = lane >> 2;
    const int schk = lane & 3;

    size_t ag[2][2], bg_[2][2];
    f16 *al[2][2], *bl[2][2];
#pragma unroll
    for (int i = 0; i < 2; ++i)
#pragma unroll
        for (int kh = 0; kh < 2; ++kh) {
            ag[i][kh]  = (size_t)(m_base + wave * 32 + i * 16 + srow) * NN + kh * 32 + schk * 8;
            al[i][kh]  = &AS[kh][(wave * 32 + i * 16) * 32];
            bg_[i][kh] = (size_t)(cl_base + wave * 32 + i * 16 + srow) * NN + kh * 32 + schk * 8;
            bl[i][kh]  = &BS[kh][(wave * 32 + i * 16) * 32];
        }

    f32x4 acc[4][4];
#pragma unroll
    for (int i = 0; i < 4; ++i)
#pragma unroll
        for (int j = 0; j < 4; ++j) acc[i][j] = (f32x4){0.f, 0.f, 0.f, 0.f};

    for (int nn0 = 0; nn0 < NN; nn0 += 64) {
#pragma unroll
        for (int i = 0; i < 2; ++i)
#pragma unroll
            for (int kh = 0; kh < 2; ++kh) {
                gll16(h + ag[i][kh] + nn0, al[i][kh]);
                gll16(wd + bg_[i][kh] + nn0, bl[i][kh]);
            }

        __syncthreads();

#pragma unroll
        for (int kh = 0; kh < 2; ++kh) {
            f16x8 af[4];
#pragma unroll
            for (int t = 0; t < 4; ++t)
                af[t] = *(const f16x8*)&AS[kh][(wm + t * 16 + lr) * 32 + quad * 8];
#pragma unroll
            for (int nt = 0; nt < 4; ++nt) {
                f16x8 b = *(const f16x8*)&BS[kh][(wn + nt * 16 + lr) * 32 + quad * 8];
#pragma unroll
                for (int mt = 0; mt < 4; ++mt)
                    acc[mt][nt] = __builtin_amdgcn_mfma_f32_16x16x32_f16(af[mt], b, acc[mt][nt], 0, 0, 0);
            }
        }

        __syncthreads();
    }

#pragma unroll
    for (int mt = 0; mt < 4; ++mt)
#pragma unroll
        for (int nt = 0; nt < 4; ++nt)
#pragma unroll
            for (int r = 0; r < 4; ++r) {
                int m = m_base + wm + mt * 16 + quad * 4 + r;
                int c = c0 + cl_base + wn + nt * 16 + lr;
                out[(size_t)m * K + c] = acc[mt][nt][r];
            }
}

extern "C" void kernel_launch(void* const* d_in, const int* in_sizes, int n_in,
                              void* d_out, int out_size, void* d_ws, size_t ws_size,
                              hipStream_t stream) {
    const float* x   = (const float*)d_in[0];
    const int*   gqw = (const int*)d_in[1];
    const float* gsc = (const float*)d_in[2];
    const int*   gqz = (const int*)d_in[3];
    const int*   uqw = (const int*)d_in[4];
    const float* usc = (const float*)d_in[5];
    const int*   uqz = (const int*)d_in[6];
    const int*   dqw = (const int*)d_in[7];
    const float* dsc = (const float*)d_in[8];
    const int*   dqz = (const int*)d_in[9];
    float* out = (float*)d_out;

    const size_t HB = (size_t)M * NN * 2;   // h: 90,177,536 B
    char* ws = (char*)d_ws;
    f16* h  = (f16*)ws;
    f16* xp = (f16*)(ws + HB);              // +33.5 MB (fits: round 3/5)

    convert_x_kernel<<<(M * K / 8) / 256, 256, 0, stream>>>(x, xp);

    // ---- gate/up: weight strips live in d_out (free until down2 runs).
    // d_out = M*K*4 = 67,108,864 B = exactly 4096 columns * (Wg'+Wu') @16KB.
    const int NCg = 4096;
    for (int n0 = 0; n0 < NN; n0 += NCg) {
        int nc = NN - n0 < NCg ? NN - n0 : NCg;   // 4096, 4096, 2816
        f16* wg = (f16*)d_out;
        f16* wu = wg + (size_t)nc * K;
        dequant_gu_strip<<<dim3(nc / 256, K / 32), 256, 0, stream>>>(
            gqw, gsc, gqz, uqw, usc, uqz, wg, wu, n0);
        gateup2_kernel<<<dim3(M / 128, nc / 64), 256, 0, stream>>>(xp, wg, wu, h, n0);
    }

    // ---- down: weight strips reuse xp region (dead) + spare ws tail.
    size_t availD = ws_size - HB;                   // >= 90 MB observed (r5)
    int KC = (int)(availD / ((size_t)NN * 2));
    KC &= ~255;                                     // multiple of 256
    if (KC > K) KC = K;
    if (KC < 256) KC = 256;                         // unreachable guard
    f16* wd = (f16*)(ws + HB);
    for (int c0 = 0; c0 < K; c0 += KC) {
        int kc = K - c0 < KC ? K - c0 : KC;
        dequant_d_strip<<<dim3(kc / 256, NN / 32), 256, 0, stream>>>(
            dqw, dsc, dqz, wd, c0);
        down2_kernel<<<dim3(M / 128, kc / 128), 256, 0, stream>>>(h, wd, out, c0);
    }
}